// Round 3
// baseline (555.015 us; speedup 1.0000x reference)
//
#include <hip/hip_runtime.h>
#include <stdint.h>

typedef float f32x4 __attribute__((ext_vector_type(4)));
typedef short bf16x8 __attribute__((ext_vector_type(8)));
typedef int   i32x4  __attribute__((ext_vector_type(4)));

#define IN_DIM   25088
#define OUT_DIM  4096
#define BATCH    64
#define SPLITS   14
#define CHUNK    1792      // IN_DIM / SPLITS
#define KBLK     256       // 1 KB contiguous per label row per step
#define NBLK     7         // KBLK*NBLK = CHUNK
#define WG_N     128
#define LSTR     264       // LDS W row stride in bf16 elems (256 + 8 pad)

#define CONV_BLOCKS 784    // convert_x: 784*256*8 = 64*25088 floats
#define PART_OFF   (4u << 20)   // partials at +4 MB in d_ws (xb is 3.2 MB)

// fp32 -> bf16 bits, round-to-nearest-even
__device__ __forceinline__ uint32_t f2bf(float f) {
    uint32_t u = __builtin_bit_cast(uint32_t, f);
    return (u + 0x7FFFu + ((u >> 16) & 1u)) >> 16;
}

// ---- kernel 1: x fp32 -> bf16 into d_ws ----
__global__ __launch_bounds__(256) void prep(const float* __restrict__ x,
                                            uint32_t* __restrict__ xb) {
    const size_t i = blockIdx.x * 256 + threadIdx.x;  // 8 floats -> 4 u32
    const float4 v0 = *(const float4*)(x + i * 8);
    const float4 v1 = *(const float4*)(x + i * 8 + 4);
    uint4 o;
    o.x = f2bf(v0.x) | (f2bf(v0.y) << 16);
    o.y = f2bf(v0.z) | (f2bf(v0.w) << 16);
    o.z = f2bf(v1.x) | (f2bf(v1.y) << 16);
    o.w = f2bf(v1.z) | (f2bf(v1.w) << 16);
    *(uint4*)(xb + i * 4) = o;
}

// ---- kernel 2: main GEMM, 1 KB-per-row label runs (DRAM page locality) ----
// Per blk step each block stages 128 rows x 1 KB of labels. A wave
// instruction covers exactly one row-chunk (64 lanes x 16 B = 1 KB
// contiguous), 4x the run length of the 250 us versions. Staging is
// 4 sub-passes, pipelined one sub ahead; next step's sub-0 loads are
// issued at the top of the consume phase so the HBM stream never drains.
__global__ __launch_bounds__(256) void qlinear_main(
    const int*      __restrict__ labels,    // [4096, 25088] int32 in [0,32)
    const float*    __restrict__ centroids, // [32]
    const uint16_t* __restrict__ xb,        // [64, 25088] bf16 (precomputed)
    float*          __restrict__ partials)  // [14][64][4096] fp32
{
    __shared__ __align__(16) uint32_t table[1024];       // pair dequant table
    __shared__ __align__(16) uint16_t wt[WG_N * LSTR];   // W tile [128][264] bf16

    const int t     = threadIdx.x;
    const int wgn   = blockIdx.x & 31;      // OUT_DIM / WG_N = 32 tiles
    const int split = blockIdx.x >> 5;      // 0..13
    const int o0    = wgn * WG_N;
    const int kbase = split * CHUNK;

    // pair table: entry i = bf16(c[i&31]) | bf16(c[i>>5])<<16 (low = earlier k)
    #pragma unroll
    for (int e = 0; e < 4; ++e) {
        const int i = t + 256 * e;
        table[i] = f2bf(centroids[i & 31]) | (f2bf(centroids[i >> 5]) << 16);
    }

    const int lane = t & 63;
    const int wave = t >> 6;      // 0..3
    const int ln   = lane & 15;
    const int lq   = lane >> 4;   // 0..3

    // staging: each thread owns 8 row-streams (rows wave*8 + j + s*32),
    // reading 16 B at byte position lane*16 of the row's 1 KB chunk
    const int rbase = wave * 8;
    const int* lb = labels + (size_t)(o0 + rbase) * IN_DIM + kbase + lane * 4;

    // x: per-lane direct A-frag pointers (xb is L2-resident)
    const uint16_t* xp[4];
    #pragma unroll
    for (int mt = 0; mt < 4; ++mt)
        xp[mt] = xb + (size_t)(mt * 16 + ln) * IN_DIM + kbase + lq * 8;

    f32x4 acc[4][2] = {};   // [batch 16s][out 16s]

    // prologue: sub-pass (blk 0, s 0)
    i32x4 cur[8];
    #pragma unroll
    for (int j = 0; j < 8; ++j)
        cur[j] = __builtin_nontemporal_load((const i32x4*)(lb + (size_t)j * IN_DIM));

    for (int blk = 0; blk < NBLK; ++blk) {
        __syncthreads();   // wt writable (prev consume done); table visible on blk 0

        // ---- stage W: 4 sub-passes of 32 rows x 1 KB, pipelined 1 ahead ----
        const int* lblk = lb + blk * KBLK;
        #pragma unroll
        for (int s = 0; s < 4; ++s) {
            i32x4 nxt[8];
            if (s < 3) {
                const int* lp = lblk + (size_t)(s + 1) * 32 * IN_DIM;
                #pragma unroll
                for (int j = 0; j < 8; ++j)
                    nxt[j] = __builtin_nontemporal_load((const i32x4*)(lp + (size_t)j * IN_DIM));
            }
            #pragma unroll
            for (int j = 0; j < 8; ++j) {
                const int row = s * 32 + rbase + j;
                uint2 w;
                w.x = table[(uint32_t)cur[j].x | ((uint32_t)cur[j].y << 5)];
                w.y = table[(uint32_t)cur[j].z | ((uint32_t)cur[j].w << 5)];
                *(uint2*)(wt + row * LSTR + lane * 4) = w;
            }
            if (s < 3) {
                #pragma unroll
                for (int j = 0; j < 8; ++j) cur[j] = nxt[j];
            }
        }
        __syncthreads();

        // ---- issue next step's sub-0 label loads: in flight across consume ----
        if (blk + 1 < NBLK) {
            const int* lp = lb + (size_t)(blk + 1) * KBLK;
            #pragma unroll
            for (int j = 0; j < 8; ++j)
                cur[j] = __builtin_nontemporal_load((const i32x4*)(lp + (size_t)j * IN_DIM));
        }

        // ---- consume: 8 k-steps of 32, x A-frags 2-ahead from L2 ----
        const size_t xoff = (size_t)blk * KBLK;
        bf16x8 a0[4], a1[4];
        #pragma unroll
        for (int mt = 0; mt < 4; ++mt) {
            a0[mt] = *(const bf16x8*)(xp[mt] + xoff);
            a1[mt] = *(const bf16x8*)(xp[mt] + xoff + 32);
        }
        #pragma unroll
        for (int ks = 0; ks < 8; ++ks) {
            bf16x8 a2[4];
            if (ks + 2 < 8) {
                #pragma unroll
                for (int mt = 0; mt < 4; ++mt)
                    a2[mt] = *(const bf16x8*)(xp[mt] + xoff + (ks + 2) * 32);
            }
            bf16x8 b[2];
            #pragma unroll
            for (int nt = 0; nt < 2; ++nt)
                b[nt] = *(const bf16x8*)(wt + (wave * 32 + nt * 16 + ln) * LSTR
                                            + ks * 32 + lq * 8);
            #pragma unroll
            for (int mt = 0; mt < 4; ++mt)
                #pragma unroll
                for (int nt = 0; nt < 2; ++nt)
                    acc[mt][nt] = __builtin_amdgcn_mfma_f32_16x16x32_bf16(
                        a0[mt], b[nt], acc[mt][nt], 0, 0, 0);
            #pragma unroll
            for (int mt = 0; mt < 4; ++mt) { a0[mt] = a1[mt]; a1[mt] = a2[mt]; }
        }
    }

    // ---- epilogue: C/D layout col=lane&15 (out), row=(lane>>4)*4+reg (batch) ----
    float* pout = partials + (size_t)split * BATCH * OUT_DIM;
    #pragma unroll
    for (int mt = 0; mt < 4; ++mt)
        #pragma unroll
        for (int nt = 0; nt < 2; ++nt) {
            const int o = o0 + wave * 32 + nt * 16 + ln;
            #pragma unroll
            for (int r = 0; r < 4; ++r)
                __builtin_nontemporal_store(
                    acc[mt][nt][r],
                    pout + (size_t)(mt * 16 + lq * 4 + r) * OUT_DIM + o);
        }
}

// ---- kernel 3: out[b][o] = bias[o] + sum_s partials[s][b][o] ----
__global__ __launch_bounds__(256) void reduce_out(
    const float* __restrict__ partials,
    const float* __restrict__ bias,
    float*       __restrict__ out) {
    const int g  = blockIdx.x * 256 + threadIdx.x;   // float4 id, 65536 total
    const int o4 = g & (OUT_DIM / 4 - 1);
    f32x4 s = *((const f32x4*)bias + o4);
    const f32x4* p = (const f32x4*)partials + g;
    #pragma unroll
    for (int sp = 0; sp < SPLITS; ++sp)
        s += p[(size_t)sp * (BATCH * OUT_DIM / 4)];
    *((f32x4*)out + g) = s;
}

extern "C" void kernel_launch(void* const* d_in, const int* in_sizes, int n_in,
                              void* d_out, int out_size, void* d_ws, size_t ws_size,
                              hipStream_t stream) {
    const float* x         = (const float*)d_in[0];
    const int*   labels    = (const int*)d_in[1];
    const float* centroids = (const float*)d_in[2];
    const float* bias      = (const float*)d_in[3];
    float* out = (float*)d_out;

    uint32_t* xb       = (uint32_t*)d_ws;                    // 3.2 MB bf16 x
    float*    partials = (float*)((char*)d_ws + PART_OFF);   // 14.7 MB

    prep<<<CONV_BLOCKS, 256, 0, stream>>>(x, xb);
    qlinear_main<<<32 * SPLITS, 256, 0, stream>>>(labels, centroids,
                                                  (const uint16_t*)xb, partials);
    reduce_out<<<BATCH * OUT_DIM / 4 / 256, 256, 0, stream>>>(partials, bias, out);
}